// Round 1
// baseline (119.505 us; speedup 1.0000x reference)
//
#include <hip/hip_runtime.h>
#include <math.h>

// Problem constants (from reference): pred [16,2,512,512] f32, mask [16,512,512] f32
// out: scalar f32 = mean_b( wbce_b + wiou_b )
#define B_   16
#define H_   512
#define W_   512
#define HW_  (H_ * W_)
#define KR   15        // radius, kernel K=31
#define KK_INV (1.0f / 961.0f)
#define MU_  5.0f
#define TH   64        // tile rows
#define TW   64        // tile cols
#define HALO_H (TH + 2*KR)   // 94
#define HALO_W (TW + 2*KR)   // 94
#define S1_N   (HALO_H * TW) // 6016

__global__ __launch_bounds__(256) void structure_loss_tile(
    const float* __restrict__ pred,   // [B,2,H,W]
    const float* __restrict__ mask,   // [B,H,W]
    float* __restrict__ acc)          // [B,4]: sum_weit, sum_weit_bce, inter, union
{
    __shared__ float tile[HALO_H * HALO_W];  // 94*94 floats = 35.3 KB (reused for s1)
    __shared__ float wsum[4][4];

    const int tid = threadIdx.x;
    const int b   = blockIdx.z;
    const int r0  = blockIdx.y * TH;
    const int c0  = blockIdx.x * TW;

    const float* mb = mask + (size_t)b * HW_;
    const float* pb = pred + ((size_t)b * 2 + 1) * HW_;   // channel 1 logits

    // ---- Phase 1: load zero-padded 94x94 mask halo into LDS ----
    const int gy0 = r0 - KR;
    const int gx0 = c0 - KR;
    for (int idx = tid; idx < HALO_H * HALO_W; idx += 256) {
        int ly = idx / HALO_W;
        int lx = idx - ly * HALO_W;
        int gy = gy0 + ly;
        int gx = gx0 + lx;
        float v = 0.0f;
        if (gy >= 0 && gy < H_ && gx >= 0 && gx < W_)
            v = mb[gy * W_ + gx];
        tile[idx] = v;
    }
    __syncthreads();

    // ---- Phase 2: horizontal 31-tap sums -> registers (6016 outputs / 256 thr) ----
    float hs[24];
    #pragma unroll
    for (int k = 0; k < 24; ++k) {
        int idx = tid + 256 * k;          // idx = ri*64 + c  (ri: halo row, c: out col)
        hs[k] = 0.0f;
        if (idx < S1_N) {
            int ri = idx >> 6;
            int c  = idx & 63;
            int base = ri * HALO_W + c;   // mask cols c .. c+30 == global c0+c-15 .. +15
            float s = 0.0f;
            #pragma unroll
            for (int d = 0; d < 31; ++d) s += tile[base + d];
            hs[k] = s;
        }
    }
    __syncthreads();
    // write back into same LDS as s1[ri][c], row stride TW=64
    #pragma unroll
    for (int k = 0; k < 24; ++k) {
        int idx = tid + 256 * k;
        if (idx < S1_N) tile[idx] = hs[k];
    }
    __syncthreads();

    // ---- Phase 3: vertical sliding sum + fused elementwise + partial reduce ----
    // thread t: column c = t&63, row group g = t>>6 handles out rows [g*16, g*16+16)
    const int c  = tid & 63;
    const int g  = tid >> 6;
    const int gc = c0 + c;

    float vs = 0.0f;
    {
        const int ri0 = g * 16;
        #pragma unroll
        for (int j = 0; j < 31; ++j) vs += tile[(ri0 + j) * TW + c];
    }

    float s_w = 0.0f, s_wb = 0.0f, s_in = 0.0f, s_un = 0.0f;
    #pragma unroll
    for (int i = 0; i < 16; ++i) {
        const int ro = g * 16 + i;        // tile-local output row
        const int r  = r0 + ro;           // global row
        const float avg = vs * KK_INV;

        const float m = mb[r * W_ + gc];
        const float p = pb[r * W_ + gc];

        const float weit = 1.0f + MU_ * fabsf(avg - m);
        const float bce  = fmaxf(p, 0.0f) - p * m + log1pf(expf(-fabsf(p)));
        const float ps   = 1.0f / (1.0f + expf(-p));

        s_w  += weit;
        s_wb += weit * bce;
        s_in += ps * m * weit;
        s_un += (ps + m) * weit;

        if (i < 15)
            vs += tile[(ro + 31) * TW + c] - tile[ro * TW + c];
    }

    // ---- block reduction: wave64 shuffle, then 4 waves -> atomics ----
    const int lane = tid & 63;
    const int wid  = tid >> 6;
    float vals[4] = { s_w, s_wb, s_in, s_un };
    #pragma unroll
    for (int s = 0; s < 4; ++s) {
        float v = vals[s];
        #pragma unroll
        for (int off = 32; off > 0; off >>= 1)
            v += __shfl_down(v, off);
        if (lane == 0) wsum[wid][s] = v;
    }
    __syncthreads();
    if (tid < 4) {
        float tot = wsum[0][tid] + wsum[1][tid] + wsum[2][tid] + wsum[3][tid];
        atomicAdd(&acc[b * 4 + tid], tot);
    }
}

__global__ void structure_loss_final(const float* __restrict__ acc,
                                     float* __restrict__ out)
{
    const int t = threadIdx.x;
    float loss = 0.0f;
    if (t < B_) {
        float sw    = acc[t * 4 + 0];
        float swb   = acc[t * 4 + 1];
        float inter = acc[t * 4 + 2];
        float uni   = acc[t * 4 + 3];
        float wbce  = swb / sw;
        float wiou  = 1.0f - (inter + 1.0f) / (uni - inter + 1.0f);
        loss = wbce + wiou;
    }
    #pragma unroll
    for (int off = 32; off > 0; off >>= 1)
        loss += __shfl_down(loss, off);
    if (t == 0) out[0] = loss * (1.0f / (float)B_);
}

extern "C" void kernel_launch(void* const* d_in, const int* in_sizes, int n_in,
                              void* d_out, int out_size, void* d_ws, size_t ws_size,
                              hipStream_t stream) {
    const float* pred = (const float*)d_in[0];  // [16,2,512,512]
    const float* mask = (const float*)d_in[1];  // [16,512,512]
    float* out = (float*)d_out;
    float* acc = (float*)d_ws;                  // 64 floats

    hipMemsetAsync(acc, 0, B_ * 4 * sizeof(float), stream);

    dim3 grid(W_ / TW, H_ / TH, B_);            // 8 x 8 x 16 = 1024 blocks
    structure_loss_tile<<<grid, 256, 0, stream>>>(pred, mask, acc);
    structure_loss_final<<<1, 64, 0, stream>>>(acc, out);
}

// Round 2
// 106.979 us; speedup vs baseline: 1.1171x; 1.1171x over previous
//
#include <hip/hip_runtime.h>
#include <math.h>

// StructureLoss: pred [16,2,512,512] f32, mask [16,512,512] f32 -> scalar f32
// loss = mean_b( wbce_b + wiou_b ), weit = 1 + 5*|boxavg31(m) - m|
#define B_   16
#define H_   512
#define W_   512
#define HW_  (H_ * W_)
#define KR   15
#define KK_INV (1.0f / 961.0f)
#define MU_  5.0f
#define TH   64
#define TW   64
#define HALO_H (TH + 2*KR)     // 94
#define HALO_W (TW + 2*KR)     // 94 valid cols
#define HSTRIDE 95             // padded (odd) row stride for mask halo
#define S1STRIDE 65            // padded (odd) row stride for s1 (94 x 64 valid)
// LDS buffer: 94*95 floats = 35720 B; s1 (94*65=6110 floats) reuses it in place.

__global__ __launch_bounds__(256) void structure_loss_tile(
    const float* __restrict__ pred,   // [B,2,H,W]
    const float* __restrict__ mask,   // [B,H,W]
    float* __restrict__ acc)          // [B,4]: sum_weit, sum_weit_bce, inter, union
{
    __shared__ float tile[HALO_H * HSTRIDE];
    __shared__ float wsum[4][4];

    const int tid = threadIdx.x;
    const int b   = blockIdx.z;
    const int r0  = blockIdx.y * TH;
    const int c0  = blockIdx.x * TW;

    const float* mb = mask + (size_t)b * HW_;
    const float* pb = pred + ((size_t)b * 2 + 1) * HW_;   // channel-1 logits

    // ---- Phase 1: load zero-padded 94x94 mask halo (row stride 95) ----
    const int gy0 = r0 - KR;
    const int gx0 = c0 - KR;
    for (int idx = tid; idx < HALO_H * HSTRIDE; idx += 256) {
        int ly = idx / HSTRIDE;
        int lx = idx - ly * HSTRIDE;
        int gy = gy0 + ly;
        int gx = gx0 + lx;
        float v = 0.0f;
        if (lx < HALO_W && gy >= 0 && gy < H_ && gx >= 0 && gx < W_)
            v = mb[gy * W_ + gx];
        tile[idx] = v;
    }
    __syncthreads();

    // ---- Phase 2: horizontal 31-tap via sliding window over 16-col chunks ----
    // 376 tasks = 94 rows x 4 chunks; task t -> row t>>2, chunk t&3.
    // Thread tid does task tid, and task tid+256 if tid < 120.
    float hsA[16], hsB[16];
    {
        const int row = tid >> 2, ch = tid & 3;
        const int base = row * HSTRIDE + ch * 16;
        float s = 0.0f;
        #pragma unroll
        for (int d = 0; d < 31; ++d) s += tile[base + d];
        hsA[0] = s;
        #pragma unroll
        for (int i = 1; i < 16; ++i) {
            s += tile[base + 30 + i] - tile[base + i - 1];
            hsA[i] = s;
        }
    }
    const bool hasB = (tid < 120);
    if (hasB) {
        const int task = tid + 256;
        const int row = task >> 2, ch = task & 3;
        const int base = row * HSTRIDE + ch * 16;
        float s = 0.0f;
        #pragma unroll
        for (int d = 0; d < 31; ++d) s += tile[base + d];
        hsB[0] = s;
        #pragma unroll
        for (int i = 1; i < 16; ++i) {
            s += tile[base + 30 + i] - tile[base + i - 1];
            hsB[i] = s;
        }
    }
    __syncthreads();   // all mask reads done; safe to overwrite buffer as s1
    {
        const int row = tid >> 2, ch = tid & 3;
        const int o = row * S1STRIDE + ch * 16;
        #pragma unroll
        for (int i = 0; i < 16; ++i) tile[o + i] = hsA[i];
    }
    if (hasB) {
        const int task = tid + 256;
        const int row = task >> 2, ch = task & 3;
        const int o = row * S1STRIDE + ch * 16;
        #pragma unroll
        for (int i = 0; i < 16; ++i) tile[o + i] = hsB[i];
    }
    __syncthreads();

    // ---- Phase 3: vertical sliding sum + fused elementwise + partial reduce ----
    // thread t: column c = t&63, row group g = t>>6 -> output rows [g*16, g*16+16)
    const int c  = tid & 63;
    const int g  = tid >> 6;
    const int gc = c0 + c;

    float vs = 0.0f;
    {
        const int ri0 = g * 16;
        #pragma unroll
        for (int j = 0; j < 31; ++j) vs += tile[(ri0 + j) * S1STRIDE + c];
    }

    float s_w = 0.0f, s_wb = 0.0f, s_in = 0.0f, s_un = 0.0f;
    #pragma unroll
    for (int i = 0; i < 16; ++i) {
        const int ro = g * 16 + i;
        const int r  = r0 + ro;
        const float avg = vs * KK_INV;

        const float m = mb[r * W_ + gc];
        const float p = pb[r * W_ + gc];

        const float weit = 1.0f + MU_ * fabsf(avg - m);
        const float bce  = fmaxf(p, 0.0f) - p * m + log1pf(expf(-fabsf(p)));
        const float ps   = 1.0f / (1.0f + expf(-p));

        s_w  += weit;
        s_wb += weit * bce;
        s_in += ps * m * weit;
        s_un += (ps + m) * weit;

        if (i < 15)
            vs += tile[(ro + 31) * S1STRIDE + c] - tile[ro * S1STRIDE + c];
    }

    // ---- block reduction ----
    const int lane = tid & 63;
    const int wid  = tid >> 6;
    float vals[4] = { s_w, s_wb, s_in, s_un };
    #pragma unroll
    for (int s = 0; s < 4; ++s) {
        float v = vals[s];
        #pragma unroll
        for (int off = 32; off > 0; off >>= 1)
            v += __shfl_down(v, off);
        if (lane == 0) wsum[wid][s] = v;
    }
    __syncthreads();
    if (tid < 4) {
        float tot = wsum[0][tid] + wsum[1][tid] + wsum[2][tid] + wsum[3][tid];
        atomicAdd(&acc[b * 4 + tid], tot);
    }
}

__global__ void structure_loss_final(const float* __restrict__ acc,
                                     float* __restrict__ out)
{
    const int t = threadIdx.x;
    float loss = 0.0f;
    if (t < B_) {
        float sw    = acc[t * 4 + 0];
        float swb   = acc[t * 4 + 1];
        float inter = acc[t * 4 + 2];
        float uni   = acc[t * 4 + 3];
        loss = swb / sw + 1.0f - (inter + 1.0f) / (uni - inter + 1.0f);
    }
    #pragma unroll
    for (int off = 32; off > 0; off >>= 1)
        loss += __shfl_down(loss, off);
    if (t == 0) out[0] = loss * (1.0f / (float)B_);
}

extern "C" void kernel_launch(void* const* d_in, const int* in_sizes, int n_in,
                              void* d_out, int out_size, void* d_ws, size_t ws_size,
                              hipStream_t stream) {
    const float* pred = (const float*)d_in[0];
    const float* mask = (const float*)d_in[1];
    float* out = (float*)d_out;
    float* acc = (float*)d_ws;   // 64 floats

    hipMemsetAsync(acc, 0, B_ * 4 * sizeof(float), stream);

    dim3 grid(W_ / TW, H_ / TH, B_);   // 8 x 8 x 16 = 1024 blocks
    structure_loss_tile<<<grid, 256, 0, stream>>>(pred, mask, acc);
    structure_loss_final<<<1, 64, 0, stream>>>(acc, out);
}

// Round 3
// 101.220 us; speedup vs baseline: 1.1806x; 1.0569x over previous
//
#include <hip/hip_runtime.h>
#include <math.h>

// StructureLoss: pred [16,2,512,512] f32, mask [16,512,512] f32 -> scalar f32
// loss = mean_b( wbce_b + wiou_b ), weit = 1 + 5*|boxavg31(m) - m|
#define B_   16
#define H_   512
#define W_   512
#define HW_  (H_ * W_)
#define KR   15
#define KK_INV (1.0f / 961.0f)
#define MU_  5.0f
#define TH   64
#define TW   64
#define HALO_H 94              // TH + 2*KR
#define HALO_W 94
#define HSTRIDE 95             // padded (odd) row stride for mask halo
#define S1STRIDE 65            // padded (odd) row stride for s1 (94 x 64 valid)

__global__ __launch_bounds__(256) void structure_loss_tile(
    const float* __restrict__ pred,     // [B,2,H,W]
    const float* __restrict__ mask,     // [B,H,W]
    float* __restrict__ partial)        // [1024][4]: sum_weit, sum_weit_bce, inter, union
{
    __shared__ float tile[HALO_H * HSTRIDE];   // 35.7 KB, reused in place for s1
    __shared__ float wsum[4][4];

    const int tid = threadIdx.x;
    const int b   = blockIdx.z;
    const int r0  = blockIdx.y * TH;
    const int c0  = blockIdx.x * TW;
    const int blk = (blockIdx.z * gridDim.y + blockIdx.y) * gridDim.x + blockIdx.x;

    const float* mb = mask + (size_t)b * HW_;
    const float* pb = pred + ((size_t)b * 2 + 1) * HW_;   // channel-1 logits

    const int c  = tid & 63;
    const int g  = tid >> 6;
    const int gc = c0 + c;

    // ---- Prefetch phase-3 (m,p) pairs into registers (overlaps LDS phases) ----
    float mreg[16], preg[16];
    #pragma unroll
    for (int i = 0; i < 16; ++i) {
        const int r = r0 + g * 16 + i;
        mreg[i] = mb[r * W_ + gc];
        preg[i] = pb[r * W_ + gc];
    }

    // ---- Phase 1: zero-padded 94x94 mask halo into LDS (row stride 95) ----
    const int gy0 = r0 - KR;
    const int gx0 = c0 - KR;
    for (int idx = tid; idx < HALO_H * HSTRIDE; idx += 256) {
        int ly = idx / HSTRIDE;
        int lx = idx - ly * HSTRIDE;
        int gy = gy0 + ly;
        int gx = gx0 + lx;
        float v = 0.0f;
        if (lx < HALO_W && gy >= 0 && gy < H_ && gx >= 0 && gx < W_)
            v = mb[gy * W_ + gx];
        tile[idx] = v;
    }
    __syncthreads();

    // ---- Phase 2: horizontal 31-tap sums, sliding window over 16-col chunks ----
    // 376 tasks = 94 rows x 4 chunks; thread tid does task tid (+ tid+256 if tid<120)
    float hsA[16], hsB[16];
    {
        const int row = tid >> 2, ch = tid & 3;
        const int base = row * HSTRIDE + ch * 16;
        float s = 0.0f;
        #pragma unroll
        for (int d = 0; d < 31; ++d) s += tile[base + d];
        hsA[0] = s;
        #pragma unroll
        for (int i = 1; i < 16; ++i) {
            s += tile[base + 30 + i] - tile[base + i - 1];
            hsA[i] = s;
        }
    }
    const bool hasB = (tid < 120);
    if (hasB) {
        const int task = tid + 256;
        const int row = task >> 2, ch = task & 3;
        const int base = row * HSTRIDE + ch * 16;
        float s = 0.0f;
        #pragma unroll
        for (int d = 0; d < 31; ++d) s += tile[base + d];
        hsB[0] = s;
        #pragma unroll
        for (int i = 1; i < 16; ++i) {
            s += tile[base + 30 + i] - tile[base + i - 1];
            hsB[i] = s;
        }
    }
    __syncthreads();   // all halo reads done; reuse buffer as s1 (stride 65)
    {
        const int row = tid >> 2, ch = tid & 3;
        const int o = row * S1STRIDE + ch * 16;
        #pragma unroll
        for (int i = 0; i < 16; ++i) tile[o + i] = hsA[i];
    }
    if (hasB) {
        const int task = tid + 256;
        const int row = task >> 2, ch = task & 3;
        const int o = row * S1STRIDE + ch * 16;
        #pragma unroll
        for (int i = 0; i < 16; ++i) tile[o + i] = hsB[i];
    }
    __syncthreads();

    // ---- Phase 3: vertical sliding sum + fused elementwise + partial reduce ----
    float vs = 0.0f;
    {
        const int ri0 = g * 16;
        #pragma unroll
        for (int j = 0; j < 31; ++j) vs += tile[(ri0 + j) * S1STRIDE + c];
    }

    float s_w = 0.0f, s_wb = 0.0f, s_in = 0.0f, s_un = 0.0f;
    #pragma unroll
    for (int i = 0; i < 16; ++i) {
        const int ro = g * 16 + i;
        const float avg = vs * KK_INV;

        const float m = mreg[i];
        const float p = preg[i];

        const float weit = 1.0f + MU_ * fabsf(avg - m);
        // e = exp(-|p|); bce = max(p,0) - p*m + log(1+e); sigmoid = (p>=0?1:e)/(1+e)
        const float e    = __expf(-fabsf(p));
        const float inv  = __builtin_amdgcn_rcpf(1.0f + e);
        const float bce  = fmaxf(p, 0.0f) - p * m + __logf(1.0f + e);
        const float ps   = (p >= 0.0f ? 1.0f : e) * inv;

        s_w  += weit;
        s_wb += weit * bce;
        s_in += ps * m * weit;
        s_un += (ps + m) * weit;

        if (i < 15)
            vs += tile[(ro + 31) * S1STRIDE + c] - tile[ro * S1STRIDE + c];
    }

    // ---- block reduction: wave shuffle -> LDS -> one store per component ----
    const int lane = tid & 63;
    const int wid  = tid >> 6;
    float vals[4] = { s_w, s_wb, s_in, s_un };
    #pragma unroll
    for (int s = 0; s < 4; ++s) {
        float v = vals[s];
        #pragma unroll
        for (int off = 32; off > 0; off >>= 1)
            v += __shfl_down(v, off);
        if (lane == 0) wsum[wid][s] = v;
    }
    __syncthreads();
    if (tid < 4) {
        float tot = wsum[0][tid] + wsum[1][tid] + wsum[2][tid] + wsum[3][tid];
        partial[blk * 4 + tid] = tot;   // unconditional write -> no memset needed
    }
}

__global__ void structure_loss_final(const float* __restrict__ partial,
                                     float* __restrict__ out)
{
    const int t = threadIdx.x;          // 64 threads
    const int bb = t >> 2;              // batch 0..15
    const int s  = t & 3;               // component
    float v = 0.0f;
    #pragma unroll 8
    for (int j = 0; j < 64; ++j)        // 64 blocks per batch
        v += partial[((bb << 6) + j) * 4 + s];

    const float v1 = __shfl_down(v, 1);
    const float v2 = __shfl_down(v, 2);
    const float v3 = __shfl_down(v, 3);
    float loss = 0.0f;
    if (s == 0) {
        const float sw = v, swb = v1, inter = v2, uni = v3;
        loss = swb / sw + 1.0f - (inter + 1.0f) / (uni - inter + 1.0f);
    }
    #pragma unroll
    for (int off = 4; off < 64; off <<= 1)
        loss += __shfl_down(loss, off);
    if (t == 0) out[0] = loss * (1.0f / (float)B_);
}

extern "C" void kernel_launch(void* const* d_in, const int* in_sizes, int n_in,
                              void* d_out, int out_size, void* d_ws, size_t ws_size,
                              hipStream_t stream) {
    const float* pred = (const float*)d_in[0];
    const float* mask = (const float*)d_in[1];
    float* out = (float*)d_out;
    float* partial = (float*)d_ws;      // 1024*4 floats, fully overwritten each call

    dim3 grid(W_ / TW, H_ / TH, B_);    // 8 x 8 x 16 = 1024 blocks
    structure_loss_tile<<<grid, 256, 0, stream>>>(pred, mask, partial);
    structure_loss_final<<<1, 64, 0, stream>>>(partial, out);
}

// Round 4
// 97.346 us; speedup vs baseline: 1.2276x; 1.0398x over previous
//
#include <hip/hip_runtime.h>
#include <math.h>

// StructureLoss: pred [16,2,512,512] f32, mask [16,512,512] f32 -> scalar f32
// loss = mean_b( wbce_b + wiou_b ), weit = 1 + 5*|boxavg31(m) - m|
#define B_   16
#define H_   512
#define W_   512
#define HW_  (H_ * W_)
#define KR   15
#define KK_INV (1.0f / 961.0f)
#define MU_  5.0f
#define TH   64
#define TW   64
#define HALO_H 94              // TH + 2*KR
#define HALO_W 94
#define HSTRIDE 95             // padded (odd) row stride for mask halo -> 2-way banks max
#define S1STRIDE 65            // padded (odd) row stride for s1 (94 x 64 valid)

__global__ __launch_bounds__(256) void structure_loss_tile(
    const float* __restrict__ pred,     // [B,2,H,W]
    const float* __restrict__ mask,     // [B,H,W]
    float* __restrict__ partial)        // [1024][4]: sum_weit, sum_weit_bce, inter, union
{
    __shared__ float tile[HALO_H * HSTRIDE];   // 35.7 KB, reused in place for s1
    __shared__ float wsum[4][4];

    const int tid = threadIdx.x;
    const int b   = blockIdx.z;
    const int r0  = blockIdx.y * TH;
    const int c0  = blockIdx.x * TW;
    const int blk = (blockIdx.z * gridDim.y + blockIdx.y) * gridDim.x + blockIdx.x;

    const float* mb = mask + (size_t)b * HW_;
    const float* pb = pred + ((size_t)b * 2 + 1) * HW_;   // channel-1 logits

    const int c  = tid & 63;
    const int g  = tid >> 6;
    const int gc = c0 + c;

    // ---- Prefetch logits into registers (overlaps the LDS phases) ----
    float preg[16];
    #pragma unroll
    for (int i = 0; i < 16; ++i) {
        const int r = r0 + g * 16 + i;
        preg[i] = pb[r * W_ + gc];
    }

    // ---- Phase 1: zero-padded 94x94 mask halo into LDS (row stride 95) ----
    const int gy0 = r0 - KR;
    const int gx0 = c0 - KR;
    for (int idx = tid; idx < HALO_H * HSTRIDE; idx += 256) {
        int ly = idx / HSTRIDE;
        int lx = idx - ly * HSTRIDE;
        int gy = gy0 + ly;
        int gx = gx0 + lx;
        float v = 0.0f;
        if (lx < HALO_W && gy >= 0 && gy < H_ && gx >= 0 && gx < W_)
            v = mb[gy * W_ + gx];
        tile[idx] = v;
    }
    __syncthreads();

    // ---- Center mask values from the halo (stride-1 within wave: conflict-free) ----
    float mreg[16];
    #pragma unroll
    for (int i = 0; i < 16; ++i)
        mreg[i] = tile[(KR + g * 16 + i) * HSTRIDE + (KR + c)];

    // ---- Phase 2: horizontal 31-tap sums, sliding window over 16-col chunks ----
    // 376 tasks = 94 rows x 4 chunks; thread tid does task tid (+ tid+256 if tid<120).
    // keep[]: the 15 taps that get subtracted were read during init -> no re-read.
    float hsA[16], hsB[16];
    {
        const int row = tid >> 2, ch = tid & 3;
        const int base = row * HSTRIDE + ch * 16;
        float keep[15];
        float s = 0.0f;
        #pragma unroll
        for (int d = 0; d < 31; ++d) {
            float t = tile[base + d];
            if (d < 15) keep[d] = t;
            s += t;
        }
        hsA[0] = s;
        #pragma unroll
        for (int i = 1; i < 16; ++i) {
            s += tile[base + 30 + i] - keep[i - 1];
            hsA[i] = s;
        }
    }
    const bool hasB = (tid < 120);
    if (hasB) {
        const int task = tid + 256;
        const int row = task >> 2, ch = task & 3;
        const int base = row * HSTRIDE + ch * 16;
        float keep[15];
        float s = 0.0f;
        #pragma unroll
        for (int d = 0; d < 31; ++d) {
            float t = tile[base + d];
            if (d < 15) keep[d] = t;
            s += t;
        }
        hsB[0] = s;
        #pragma unroll
        for (int i = 1; i < 16; ++i) {
            s += tile[base + 30 + i] - keep[i - 1];
            hsB[i] = s;
        }
    }
    __syncthreads();   // all halo reads done; reuse buffer as s1 (stride 65)
    {
        const int row = tid >> 2, ch = tid & 3;
        const int o = row * S1STRIDE + ch * 16;
        #pragma unroll
        for (int i = 0; i < 16; ++i) tile[o + i] = hsA[i];
    }
    if (hasB) {
        const int task = tid + 256;
        const int row = task >> 2, ch = task & 3;
        const int o = row * S1STRIDE + ch * 16;
        #pragma unroll
        for (int i = 0; i < 16; ++i) tile[o + i] = hsB[i];
    }
    __syncthreads();

    // ---- Phase 3: vertical sliding sum + fused elementwise + partial reduce ----
    const int ri0 = g * 16;
    float vkeep[15];
    float vs = 0.0f;
    #pragma unroll
    for (int j = 0; j < 31; ++j) {
        float t = tile[(ri0 + j) * S1STRIDE + c];
        if (j < 15) vkeep[j] = t;
        vs += t;
    }

    float s_w = 0.0f, s_wb = 0.0f, s_in = 0.0f, s_un = 0.0f;
    #pragma unroll
    for (int i = 0; i < 16; ++i) {
        const int ro = ri0 + i;
        const float avg = vs * KK_INV;

        const float m = mreg[i];
        const float p = preg[i];

        const float weit = 1.0f + MU_ * fabsf(avg - m);
        // e = exp(-|p|); bce = max(p,0) - p*m + log(1+e); sigmoid = (p>=0?1:e)/(1+e)
        const float e    = __expf(-fabsf(p));
        const float inv  = __builtin_amdgcn_rcpf(1.0f + e);
        const float bce  = fmaxf(p, 0.0f) - p * m + __logf(1.0f + e);
        const float ps   = (p >= 0.0f ? 1.0f : e) * inv;

        s_w  += weit;
        s_wb += weit * bce;
        s_in += ps * m * weit;
        s_un += (ps + m) * weit;

        if (i < 15)
            vs += tile[(ro + 31) * S1STRIDE + c] - vkeep[i];
    }

    // ---- block reduction: wave shuffle -> LDS -> one store per component ----
    const int lane = tid & 63;
    const int wid  = tid >> 6;
    float vals[4] = { s_w, s_wb, s_in, s_un };
    #pragma unroll
    for (int s = 0; s < 4; ++s) {
        float v = vals[s];
        #pragma unroll
        for (int off = 32; off > 0; off >>= 1)
            v += __shfl_down(v, off);
        if (lane == 0) wsum[wid][s] = v;
    }
    __syncthreads();
    if (tid < 4) {
        float tot = wsum[0][tid] + wsum[1][tid] + wsum[2][tid] + wsum[3][tid];
        partial[blk * 4 + tid] = tot;   // unconditional write -> no memset needed
    }
}

__global__ void structure_loss_final(const float* __restrict__ partial,
                                     float* __restrict__ out)
{
    // 64 threads; 4 threads per batch, 16 blocks each, float4-coalesced.
    const int t = threadIdx.x;
    const float4* p4 = (const float4*)partial;   // one float4 per block
    float4 v = make_float4(0.f, 0.f, 0.f, 0.f);
    #pragma unroll
    for (int j = 0; j < 16; ++j) {
        float4 q = p4[t * 16 + j];
        v.x += q.x; v.y += q.y; v.z += q.z; v.w += q.w;
    }
    // reduce the 4 threads of each batch group
    #pragma unroll
    for (int off = 2; off > 0; off >>= 1) {
        v.x += __shfl_down(v.x, off);
        v.y += __shfl_down(v.y, off);
        v.z += __shfl_down(v.z, off);
        v.w += __shfl_down(v.w, off);
    }
    float loss = 0.0f;
    if ((t & 3) == 0) {
        const float sw = v.x, swb = v.y, inter = v.z, uni = v.w;
        loss = swb / sw + 1.0f - (inter + 1.0f) / (uni - inter + 1.0f);
    }
    #pragma unroll
    for (int off = 32; off >= 4; off >>= 1)
        loss += __shfl_down(loss, off);
    if (t == 0) out[0] = loss * (1.0f / (float)B_);
}

extern "C" void kernel_launch(void* const* d_in, const int* in_sizes, int n_in,
                              void* d_out, int out_size, void* d_ws, size_t ws_size,
                              hipStream_t stream) {
    const float* pred = (const float*)d_in[0];
    const float* mask = (const float*)d_in[1];
    float* out = (float*)d_out;
    float* partial = (float*)d_ws;      // 1024*4 floats, fully overwritten each call

    dim3 grid(W_ / TW, H_ / TH, B_);    // 8 x 8 x 16 = 1024 blocks
    structure_loss_tile<<<grid, 256, 0, stream>>>(pred, mask, partial);
    structure_loss_final<<<1, 64, 0, stream>>>(partial, out);
}

// Round 5
// 94.553 us; speedup vs baseline: 1.2639x; 1.0295x over previous
//
#include <hip/hip_runtime.h>
#include <math.h>

// StructureLoss: pred [16,2,512,512] f32, mask [16,512,512] f32 -> scalar f32
// loss = mean_b( wbce_b + wiou_b ), weit = 1 + 5*|boxavg31(m) - m|
//
// R5 structure: vertical 31-row sliding sums straight from global (coalesced),
// ONE LDS round-trip (vsum 64x94, stride 95), one barrier, then horizontal
// 31-tap slide fused with the elementwise math (m/p via aligned float4).
#define B_   16
#define H_   512
#define W_   512
#define HW_  (H_ * W_)
#define KR   15
#define KK_INV (1.0f / 961.0f)
#define MU_  5.0f
#define TH   64
#define TW   64
#define HALO_W 94              // TW + 2*KR
#define VSTRIDE 95             // odd stride -> horizontal reads exactly 2-way (free)

__global__ __launch_bounds__(256) void structure_loss_tile(
    const float* __restrict__ pred,     // [B,2,H,W]
    const float* __restrict__ mask,     // [B,H,W]
    float* __restrict__ partial)        // [1024][4]
{
    __shared__ float vt[TH * VSTRIDE];  // 64 x 95 floats = 24.3 KB
    __shared__ float wsum[4][4];

    const int tid = threadIdx.x;
    const int b   = blockIdx.z;
    const int r0  = blockIdx.y * TH;
    const int c0  = blockIdx.x * TW;
    const int blk = (blockIdx.z * gridDim.y + blockIdx.y) * gridDim.x + blockIdx.x;

    const float* mb = mask + (size_t)b * HW_;
    const float* pb = pred + ((size_t)b * 2 + 1) * HW_;   // channel-1 logits

    // ---- Vertical phase: 376 tasks = 4 row-groups x 94 halo cols ----
    // task t: rg = t/94, cc = t%94; column gx = c0-15+cc (zero outside image).
    // Produces vt[rg*16+i][cc] = sum_{dr=-15..15} mask[r0+rg*16+i+dr][gx].
    // Lane->cc mapping is consecutive -> global reads coalesced per step.
    auto vtask = [&](int task) {
        const int rg = task / 94;
        const int cc = task - rg * 94;
        const int gx = c0 - KR + cc;
        const bool xok = ((unsigned)gx < (unsigned)W_);
        const float* colp = mb + gx;
        const int gy0 = r0 + rg * 16 - KR;
        float keep[15];
        float s = 0.0f;
        #pragma unroll
        for (int d = 0; d < 31; ++d) {
            const int gy = gy0 + d;
            float v = 0.0f;
            if (xok && (unsigned)gy < (unsigned)H_) v = colp[gy * W_];
            if (d < 15) keep[d] = v;
            s += v;
        }
        const int o = (rg * 16) * VSTRIDE + cc;
        vt[o] = s;
        #pragma unroll
        for (int i = 1; i < 16; ++i) {
            const int gy = gy0 + 30 + i;
            float v = 0.0f;
            if (xok && (unsigned)gy < (unsigned)H_) v = colp[gy * W_];
            s += v - keep[i - 1];
            vt[o + i * VSTRIDE] = s;
        }
    };
    vtask(tid);
    if (tid < 120) vtask(tid + 256);
    __syncthreads();

    // ---- Horizontal phase + fused elementwise ----
    // thread t: row r = t>>2, chunk ch = t&3 -> output cols [ch*16, ch*16+16)
    const int r  = tid >> 2;
    const int ch = tid & 3;
    const int gr = r0 + r;
    const int gcb = c0 + ch * 16;       // 64B-aligned

    float mv[16], pv[16];
    {
        const float4* m4 = (const float4*)(mb + gr * W_ + gcb);
        const float4* p4 = (const float4*)(pb + gr * W_ + gcb);
        #pragma unroll
        for (int q = 0; q < 4; ++q) {
            const float4 a = m4[q];
            const float4 pp = p4[q];
            mv[q*4+0]=a.x;  mv[q*4+1]=a.y;  mv[q*4+2]=a.z;  mv[q*4+3]=a.w;
            pv[q*4+0]=pp.x; pv[q*4+1]=pp.y; pv[q*4+2]=pp.z; pv[q*4+3]=pp.w;
        }
    }

    const int base = r * VSTRIDE + ch * 16;
    float keep[15];
    float s = 0.0f;
    #pragma unroll
    for (int d = 0; d < 31; ++d) {
        const float t = vt[base + d];
        if (d < 15) keep[d] = t;
        s += t;
    }

    float s_w = 0.0f, s_wb = 0.0f, s_in = 0.0f, s_un = 0.0f;
    #pragma unroll
    for (int j = 0; j < 16; ++j) {
        const float avg = s * KK_INV;
        const float m = mv[j];
        const float p = pv[j];

        const float weit = 1.0f + MU_ * fabsf(avg - m);
        // e = exp(-|p|); bce = max(p,0) - p*m + log(1+e); sigmoid = (p>=0?1:e)/(1+e)
        const float e    = __expf(-fabsf(p));
        const float inv  = __builtin_amdgcn_rcpf(1.0f + e);
        const float bce  = fmaxf(p, 0.0f) - p * m + __logf(1.0f + e);
        const float ps   = (p >= 0.0f ? 1.0f : e) * inv;

        s_w  += weit;
        s_wb += weit * bce;
        s_in += ps * m * weit;
        s_un += (ps + m) * weit;

        if (j < 15)
            s += vt[base + 31 + j] - keep[j];
    }

    // ---- block reduction: wave shuffle -> LDS -> one store per component ----
    const int lane = tid & 63;
    const int wid  = tid >> 6;
    float vals[4] = { s_w, s_wb, s_in, s_un };
    #pragma unroll
    for (int q = 0; q < 4; ++q) {
        float v = vals[q];
        #pragma unroll
        for (int off = 32; off > 0; off >>= 1)
            v += __shfl_down(v, off);
        if (lane == 0) wsum[wid][q] = v;
    }
    __syncthreads();
    if (tid < 4) {
        const float tot = wsum[0][tid] + wsum[1][tid] + wsum[2][tid] + wsum[3][tid];
        partial[blk * 4 + tid] = tot;   // unconditional write -> no memset needed
    }
}

__global__ void structure_loss_final(const float* __restrict__ partial,
                                     float* __restrict__ out)
{
    // 64 threads; 4 threads per batch, 16 float4 blocks each, coalesced.
    const int t = threadIdx.x;
    const float4* p4 = (const float4*)partial;   // one float4 per block
    float4 v = make_float4(0.f, 0.f, 0.f, 0.f);
    #pragma unroll
    for (int j = 0; j < 16; ++j) {
        const float4 q = p4[t * 16 + j];
        v.x += q.x; v.y += q.y; v.z += q.z; v.w += q.w;
    }
    #pragma unroll
    for (int off = 2; off > 0; off >>= 1) {
        v.x += __shfl_down(v.x, off);
        v.y += __shfl_down(v.y, off);
        v.z += __shfl_down(v.z, off);
        v.w += __shfl_down(v.w, off);
    }
    float loss = 0.0f;
    if ((t & 3) == 0) {
        const float sw = v.x, swb = v.y, inter = v.z, uni = v.w;
        loss = swb / sw + 1.0f - (inter + 1.0f) / (uni - inter + 1.0f);
    }
    #pragma unroll
    for (int off = 32; off >= 4; off >>= 1)
        loss += __shfl_down(loss, off);
    if (t == 0) out[0] = loss * (1.0f / (float)B_);
}

extern "C" void kernel_launch(void* const* d_in, const int* in_sizes, int n_in,
                              void* d_out, int out_size, void* d_ws, size_t ws_size,
                              hipStream_t stream) {
    const float* pred = (const float*)d_in[0];
    const float* mask = (const float*)d_in[1];
    float* out = (float*)d_out;
    float* partial = (float*)d_ws;      // 1024*4 floats, fully overwritten each call

    dim3 grid(W_ / TW, H_ / TH, B_);    // 8 x 8 x 16 = 1024 blocks
    structure_loss_tile<<<grid, 256, 0, stream>>>(pred, mask, partial);
    structure_loss_final<<<1, 64, 0, stream>>>(partial, out);
}